// Round 6
// baseline (184.544 us; speedup 1.0000x reference)
//
#include <hip/hip_runtime.h>
#include <math.h>

typedef unsigned short u16;
typedef unsigned int u32;
typedef __attribute__((ext_vector_type(8))) short bf16x8;
typedef __attribute__((ext_vector_type(4))) float f32x4;

#define AS1 __attribute__((address_space(1)))
#define AS3 __attribute__((address_space(3)))

static __device__ __forceinline__ u16 f2b(float f) {
  u32 u = __float_as_uint(f);
  return (u16)((u + 0x7FFFu + ((u >> 16) & 1u)) >> 16);
}
static __device__ __forceinline__ float b2f(u16 b) {
  return __uint_as_float(((u32)b) << 16);
}

// ---------------------------------------------------------------------------
// prep: cast x (4096x1024) -> bf16; P (2048x64) -> bf16 (+ guard row 2048);
//       W (1024x3072) -> Wt bf16 TRANSPOSED [3072][1024] via LDS tiles.
// ---------------------------------------------------------------------------
__global__ __launch_bounds__(256) void prep(
    const float* __restrict__ x, const float* __restrict__ W,
    const float* __restrict__ P,
    u16* __restrict__ xb, u16* __restrict__ Wt, u16* __restrict__ Pb)
{
  __shared__ u16 sT[64 * 68];
  const int bid = blockIdx.x, t = threadIdx.x;
  if (bid < 4096) {
    const size_t base = (size_t)bid * 1024 + t * 4;
    const float4 v = *(const float4*)(x + base);
    const u32 lo = (u32)f2b(v.x) | ((u32)f2b(v.y) << 16);
    const u32 hi = (u32)f2b(v.z) | ((u32)f2b(v.w) << 16);
    *(uint2*)(xb + base) = make_uint2(lo, hi);
  } else if (bid < 4224) {
    const size_t base = (size_t)(bid - 4096) * 1024 + t * 4;
    const float4 v = *(const float4*)(P + base);
    const u32 lo = (u32)f2b(v.x) | ((u32)f2b(v.y) << 16);
    const u32 hi = (u32)f2b(v.z) | ((u32)f2b(v.w) << 16);
    *(uint2*)(Pb + base) = make_uint2(lo, hi);
  } else if (bid < 4992) {
    const int tb = bid - 4224;
    const int tk = tb / 48, tn = tb % 48;
    const int k0 = tk * 64, n0 = tn * 64;
#pragma unroll
    for (int it = 0; it < 4; ++it) {
      const int c = it * 256 + t;
      const int r = c >> 4, c4 = (c & 15) << 2;
      const float4 v = *(const float4*)(W + (size_t)(k0 + r) * 3072 + n0 + c4);
      sT[(c4 + 0) * 68 + r] = f2b(v.x);
      sT[(c4 + 1) * 68 + r] = f2b(v.y);
      sT[(c4 + 2) * 68 + r] = f2b(v.z);
      sT[(c4 + 3) * 68 + r] = f2b(v.w);
    }
    __syncthreads();
#pragma unroll
    for (int it = 0; it < 4; ++it) {
      const int c = it * 256 + t;
      const int rr = c >> 4, k4 = (c & 15) << 2;
      const uint2 rv = *(const uint2*)(sT + rr * 68 + k4);
      *(uint2*)(Wt + (size_t)(n0 + rr) * 1024 + k0 + k4) = rv;
    }
  } else {
    if (t < 64) Pb[2048 * 64 + t] = f2b(P[2047 * 64 + t]);  // guard row
  }
}

// ---------------------------------------------------------------------------
// qkv_gemm (bf16 MFMA): C = xb(4096x1024) @ Wt^T(1024x3072) + bias.
// 128x128 tile, BK=64, XOR-swizzled LDS, global_load_lds 16B.
// XCD-aware 1-D grid (768): each XCD owns 3 contiguous n-tiles so its
// 0.75 MB B-slice stays resident in the XCD-private L2 across all m-tiles.
// Epilogue: LDS repack -> coalesced stores; V goes TRANSPOSED to Vt.
// ---------------------------------------------------------------------------
__global__ __launch_bounds__(256, 3) void qkv_gemm(
    const u16* __restrict__ xb, const u16* __restrict__ Wt,
    const float* __restrict__ bq,
    u16* __restrict__ Qh, u16* __restrict__ Kh, u16* __restrict__ Vt)
{
  __shared__ u16 smem[16384];        // 32 KB: sA | sB, reused as repack tile
  u16* const sA = smem;
  u16* const sB = smem + 8192;
  u16* const T  = smem;              // epilogue tile [64][136]
  const int t = threadIdx.x;
  const int lane = t & 63, w = t >> 6;
  const int l = lane & 15, ql = lane >> 4;
  const int wm = w & 1, wn = w >> 1;
  // XCD swizzle: vid -> (xcd = vid&7 owns n-tiles 3*xcd..3*xcd+2)
  const int vid = blockIdx.x;
  const int xcd = vid & 7, jj = vid >> 3;          // jj in [0,96)
  const int n0 = (xcd * 3 + (jj % 3)) * 128;
  const int m0 = (jj / 3) * 128;

  f32x4 acc[4][4];
#pragma unroll
  for (int i = 0; i < 4; ++i)
#pragma unroll
    for (int j = 0; j < 4; ++j) acc[i][j] = (f32x4){0.f, 0.f, 0.f, 0.f};

  for (int k0 = 0; k0 < 1024; k0 += 64) {
    __syncthreads();
#pragma unroll
    for (int j = 0; j < 4; ++j) {
      const int ii = w * 4 + j;
      const int m = ii * 8 + (lane >> 3);
      const int q8 = (lane & 7) ^ (m & 7);
      __builtin_amdgcn_global_load_lds(
          (const AS1 u32*)(xb + (size_t)(m0 + m) * 1024 + k0 + q8 * 8),
          (AS3 u32*)(sA + ii * 512), 16, 0, 0);
      __builtin_amdgcn_global_load_lds(
          (const AS1 u32*)(Wt + (size_t)(n0 + m) * 1024 + k0 + q8 * 8),
          (AS3 u32*)(sB + ii * 512), 16, 0, 0);
    }
    __syncthreads();
#pragma unroll
    for (int ks = 0; ks < 2; ++ks) {
      bf16x8 a[4], b[4];
#pragma unroll
      for (int mt = 0; mt < 4; ++mt) {
        const int m = wm * 64 + mt * 16 + l;
        a[mt] = *(const bf16x8*)(sA + m * 64 + (((ks * 4 + ql) ^ (m & 7)) * 8));
      }
#pragma unroll
      for (int nt = 0; nt < 4; ++nt) {
        const int nn = wn * 64 + nt * 16 + l;
        b[nt] = *(const bf16x8*)(sB + nn * 64 + (((ks * 4 + ql) ^ (nn & 7)) * 8));
      }
#pragma unroll
      for (int mt = 0; mt < 4; ++mt)
#pragma unroll
        for (int nt = 0; nt < 4; ++nt)
          acc[mt][nt] = __builtin_amdgcn_mfma_f32_16x16x32_bf16(
              a[mt], b[nt], acc[mt][nt], 0, 0, 0);
    }
  }

  // epilogue: repack through LDS (2 passes of 64 rows), coalesced stores
  const int which = n0 >> 10;                 // 0=Q 1=K 2=V (uniform per block)
  const int qbase = m0 & 1023;
  const int bb = m0 >> 10;
  const int h0 = (n0 & 1023) >> 6;
#pragma unroll
  for (int pass = 0; pass < 2; ++pass) {
    __syncthreads();
    if (wm == pass) {
#pragma unroll
      for (int nt = 0; nt < 4; ++nt) {
        const int col = wn * 64 + nt * 16 + l;
        const float bias = bq[n0 + col];
#pragma unroll
        for (int mt = 0; mt < 4; ++mt)
#pragma unroll
          for (int rg = 0; rg < 4; ++rg)
            T[(mt * 16 + ql * 4 + rg) * 136 + col] = f2b(acc[mt][nt][rg] + bias);
      }
    }
    __syncthreads();
    if (which < 2) {
      u16* const dst = which ? Kh : Qh;
#pragma unroll
      for (int h = 0; h < 2; ++h) {
        const size_t bnoff = ((size_t)(bb * 16 + h0 + h)) << 16;
#pragma unroll
        for (int it = 0; it < 2; ++it) {
          const int c = it * 256 + t;
          const int r = c >> 3, d8 = (c & 7) * 8;
          const uint4 v = *(const uint4*)(T + r * 136 + h * 64 + d8);
          *(uint4*)(dst + bnoff + ((size_t)(qbase + pass * 64 + r) << 6) + d8) = v;
        }
      }
    } else {
#pragma unroll
      for (int h = 0; h < 2; ++h) {
        const size_t bnoff = ((size_t)(bb * 16 + h0 + h)) << 16;
#pragma unroll
        for (int it = 0; it < 2; ++it) {
          const int c = it * 256 + t;
          const int dr = c >> 3, q8 = (c & 7) * 8;
          u32 pk[4];
#pragma unroll
          for (int e = 0; e < 4; ++e) {
            const u16 lo = T[(q8 + 2 * e + 0) * 136 + h * 64 + dr];
            const u16 hi = T[(q8 + 2 * e + 1) * 136 + h * 64 + dr];
            pk[e] = (u32)lo | ((u32)hi << 16);
          }
          *(uint4*)(Vt + bnoff + ((size_t)dr << 10) + qbase + pass * 64 + q8) =
              make_uint4(pk[0], pk[1], pk[2], pk[3]);
        }
      }
    }
  }
}

// ---------------------------------------------------------------------------
// rel_attn (bf16 MFMA flash, no-max softmax): one 64-row q-tile per block.
// 1-D grid 1024, XCD-aware: bn = (vid>>7)*8 + (vid&7) puts all 16 q-tiles
// of a head on one XCD (per-XCD K/V working set 2 MB < 4 MB L2).
// LDS 40 KB; sProb is the round-4-proven conflict-free [64][64] swizzle.
//   p = exp2(s * 0.125*log2e); row-sum deferred to one epilogue reduce.
// ---------------------------------------------------------------------------
__global__ __launch_bounds__(256, 4) void rel_attn(
    const u16* __restrict__ Qh, const u16* __restrict__ Kh,
    const u16* __restrict__ Vt, const u16* __restrict__ Pb,
    const float* __restrict__ rrb, const float* __restrict__ rwb,
    float* __restrict__ out)
{
  __shared__ u16 smem[20480];        // 40960 B
  u16* const sK    = smem;           // [64][64] swizzled
  u16* const sVT   = smem + 4096;    // [64][64] swizzled (rows=d, cols=j)
  u16* const sProb = smem + 8192;    // [64][64] swizzled
  u16* const sP    = smem + 12288;   // [128][64] swizzled
  u16* const sU    = sP;             // transient alias (read once into regs)
  u16* const sW    = sP + 4096;      // transient alias

  const int t = threadIdx.x;
  const int lane = t & 63, w = t >> 6;
  const int l = lane & 15, ql = lane >> 4;
  // XCD swizzle: same head -> same XCD slot
  const int vid = blockIdx.x;
  const int bn = ((vid >> 7) << 3) | (vid & 7);    // head-batch 0..63
  const int qt = (vid >> 3) & 15;
  const int n = bn & 15, bb = bn >> 4;
  const size_t hoff = (size_t)bn << 16;
  const int cq = 3 - w;
  const int q0 = qt << 6;

  // stage U = Q+rr, W = Q+rw+K (query rows), swizzled pitch-64
#pragma unroll
  for (int it = 0; it < 2; ++it) {
    const int c = it * 256 + t;
    const int i = c >> 3, ch = c & 7;
    const int d8 = ch * 8;
    const uint4 qv = *(const uint4*)(Qh + hoff + ((size_t)(q0 + i) << 6) + d8);
    const uint4 kv = *(const uint4*)(Kh + hoff + ((size_t)(q0 + i) << 6) + d8);
    const u16* qp = (const u16*)&qv;
    const u16* kp = (const u16*)&kv;
    u16 uo[8], wo[8];
#pragma unroll
    for (int e = 0; e < 8; ++e) {
      const float rv = rrb[n * 64 + d8 + e];
      const float wv = rwb[n * 64 + d8 + e];
      const float qf = b2f(qp[e]), kf = b2f(kp[e]);
      uo[e] = f2b(qf + rv);
      wo[e] = f2b(qf + wv + kf);
    }
    const int pos = i * 64 + ((ch ^ (i & 7)) * 8);
    *(uint4*)(sU + pos) = *(const uint4*)uo;
    *(uint4*)(sW + pos) = *(const uint4*)wo;
  }
  __syncthreads();

  bf16x8 au[2], aw[2];
#pragma unroll
  for (int ks = 0; ks < 2; ++ks) {   // loop-invariant A-frags
    const int row = w * 16 + l;
    const int off = row * 64 + (((ks * 4 + ql) ^ (row & 7)) * 8);
    au[ks] = *(const bf16x8*)(sU + off);
    aw[ks] = *(const bf16x8*)(sW + off);
  }

  f32x4 o[4];
  float lrun[4];
#pragma unroll
  for (int ii = 0; ii < 4; ++ii) {
    o[ii] = (f32x4){0.f, 0.f, 0.f, 0.f};
    lrun[ii] = 0.f;
  }

  for (int k0 = 0; k0 < 1024; k0 += 64) {
    const int lb = 961 + k0 - q0;    // 1024 + k0 - q0 - 63, in [1, 1921]
    __syncthreads();
    // async staging: sK (2 calls/wave), sVT (2), sP (4)
#pragma unroll
    for (int j = 0; j < 2; ++j) {
      const int ii = w * 2 + j;
      const int m = ii * 8 + (lane >> 3);
      const int q8 = (lane & 7) ^ (m & 7);
      __builtin_amdgcn_global_load_lds(
          (const AS1 u32*)(Kh + hoff + ((size_t)(k0 + m) << 6) + q8 * 8),
          (AS3 u32*)(sK + ii * 512), 16, 0, 0);
      __builtin_amdgcn_global_load_lds(
          (const AS1 u32*)(Vt + hoff + ((size_t)m << 10) + k0 + q8 * 8),
          (AS3 u32*)(sVT + ii * 512), 16, 0, 0);
    }
#pragma unroll
    for (int j = 0; j < 4; ++j) {
      const int ii = w * 4 + j;
      const int m = ii * 8 + (lane >> 3);
      const int q8 = (lane & 7) ^ (m & 7);
      __builtin_amdgcn_global_load_lds(
          (const AS1 u32*)(Pb + ((size_t)(lb + m) << 6) + q8 * 8),
          (AS3 u32*)(sP + ii * 512), 16, 0, 0);
    }
    __syncthreads();

    f32x4 z1[4], z2[5];
#pragma unroll
    for (int i = 0; i < 4; ++i) z1[i] = (f32x4){0.f, 0.f, 0.f, 0.f};
#pragma unroll
    for (int i = 0; i < 5; ++i) z2[i] = (f32x4){0.f, 0.f, 0.f, 0.f};
#pragma unroll
    for (int ks = 0; ks < 2; ++ks) {
#pragma unroll
      for (int nt = 0; nt < 4; ++nt) {
        const int row = nt * 16 + l;
        const bf16x8 bk =
            *(const bf16x8*)(sK + row * 64 + (((ks * 4 + ql) ^ (row & 7)) * 8));
        z1[nt] = __builtin_amdgcn_mfma_f32_16x16x32_bf16(au[ks], bk, z1[nt], 0, 0, 0);
      }
#pragma unroll
      for (int li2 = 0; li2 < 5; ++li2) {
        const int row = (li2 + cq) * 16 + l;
        const bf16x8 bp =
            *(const bf16x8*)(sP + row * 64 + (((ks * 4 + ql) ^ (row & 7)) * 8));
        z2[li2] = __builtin_amdgcn_mfma_f32_16x16x32_bf16(aw[ks], bp, z2[li2], 0, 0, 0);
      }
    }

    // diagonal gather + exp2 (rows i = 16w + 4*ql + ii); no max, no reduce
    float p[4][4];
#pragma unroll
    for (int ii = 0; ii < 4; ++ii) {
      const int ci = 15 - ql * 4 - ii;                 // c & 15 (c = 63-i)
      const int src = (lane & 48) | ((l + ci) & 15);
      const bool wrap = l < ci;
#pragma unroll
      for (int jt = 0; jt < 4; ++jt) {
        const float val = wrap ? z2[jt + 1][ii] : z2[jt][ii];
        const float g = __shfl(val, src, 64);
        const float pv = exp2f((z1[jt][ii] + g) * 0.18033688011112042f);
        p[ii][jt] = pv;
        lrun[ii] += pv;
      }
    }

    // probs -> LDS (wave-private rows), round-4 conflict-free swizzle
#pragma unroll
    for (int ii = 0; ii < 4; ++ii) {
      const int r = w * 16 + ql * 4 + ii;
#pragma unroll
      for (int jt = 0; jt < 4; ++jt) {
        const int ch = jt * 2 + (l >> 3);
        sProb[r * 64 + ((ch ^ (r & 7)) * 8) + (l & 7)] = f2b(p[ii][jt]);
      }
    }

    // PV: O += Prob · V   (wave-private sProb rows: no barrier needed)
#pragma unroll
    for (int ks = 0; ks < 2; ++ks) {
      const int ar = w * 16 + l;
      const bf16x8 ap =
          *(const bf16x8*)(sProb + ar * 64 + (((ks * 4 + ql) ^ (ar & 7)) * 8));
#pragma unroll
      for (int dt = 0; dt < 4; ++dt) {
        const int row = dt * 16 + l;
        const bf16x8 bv =
            *(const bf16x8*)(sVT + row * 64 + (((ks * 4 + ql) ^ (row & 7)) * 8));
        o[dt] = __builtin_amdgcn_mfma_f32_16x16x32_bf16(ap, bv, o[dt], 0, 0, 0);
      }
    }
  }

  // epilogue: single row-sum reduce, normalize, store fp32 (B, L, D)
#pragma unroll
  for (int ii = 0; ii < 4; ++ii) {
    float ls = lrun[ii];
    ls += __shfl_xor(ls, 1);
    ls += __shfl_xor(ls, 2);
    ls += __shfl_xor(ls, 4);
    ls += __shfl_xor(ls, 8);
    const float inv = 1.f / ls;
    const int q = q0 + w * 16 + ql * 4 + ii;
#pragma unroll
    for (int dt = 0; dt < 4; ++dt)
      out[((size_t)(bb * 1024 + q) << 10) + (n << 6) + dt * 16 + l] =
          o[dt][ii] * inv;
  }
}

// ---------------------------------------------------------------------------
extern "C" void kernel_launch(void* const* d_in, const int* in_sizes, int n_in,
                              void* d_out, int out_size, void* d_ws, size_t ws_size,
                              hipStream_t stream) {
  const float* x  = (const float*)d_in[0];  // (4,1024,1024)
  const float* P  = (const float*)d_in[1];  // (2048,64)
  const float* Wq = (const float*)d_in[2];  // (1024,3072)
  const float* bq = (const float*)d_in[3];  // (3072,)
  const float* rr = (const float*)d_in[4];  // (16,64)
  const float* rw = (const float*)d_in[5];  // (16,64)
  float* out = (float*)d_out;

  char* ws = (char*)d_ws;
  u16* xb = (u16*)(ws);                      // 8 MB
  u16* Wt = (u16*)(ws + 8388608);            // 6 MB  [3072][1024]
  u16* Pb = (u16*)(ws + 14680064);           // 2049 rows x 64 (+guard)
  u16* Qh = (u16*)(ws + 14946304);           // 8 MB  [bn][q][d]
  u16* Kh = (u16*)(ws + 23334912);           // 8 MB
  u16* Vt = (u16*)(ws + 31723520);           // 8 MB  [bn][d][q]

  prep<<<4993, 256, 0, stream>>>(x, Wq, P, xb, Wt, Pb);
  qkv_gemm<<<768, 256, 0, stream>>>(xb, Wt, bq, Qh, Kh, Vt);
  rel_attn<<<1024, 256, 0, stream>>>(Qh, Kh, Vt, Pb, rr, rw, out);
}

// Round 7
// 175.507 us; speedup vs baseline: 1.0515x; 1.0515x over previous
//
#include <hip/hip_runtime.h>
#include <math.h>

typedef unsigned short u16;
typedef unsigned int u32;
typedef __attribute__((ext_vector_type(8))) short bf16x8;
typedef __attribute__((ext_vector_type(4))) float f32x4;

#define AS1 __attribute__((address_space(1)))
#define AS3 __attribute__((address_space(3)))

static __device__ __forceinline__ u16 f2b(float f) {
  u32 u = __float_as_uint(f);
  return (u16)((u + 0x7FFFu + ((u >> 16) & 1u)) >> 16);
}
static __device__ __forceinline__ u16 f2b_fast(float f) {   // round-half-up
  return (u16)((__float_as_uint(f) + 0x8000u) >> 16);
}
static __device__ __forceinline__ float b2f(u16 b) {
  return __uint_as_float(((u32)b) << 16);
}

// ---------------------------------------------------------------------------
// prep: cast x (4096x1024) -> bf16; P (2048x64) -> bf16 (+ guard row 2048);
//       W (1024x3072) -> Wt bf16 TRANSPOSED [3072][1024] via LDS tiles.
// ---------------------------------------------------------------------------
__global__ __launch_bounds__(256) void prep(
    const float* __restrict__ x, const float* __restrict__ W,
    const float* __restrict__ P,
    u16* __restrict__ xb, u16* __restrict__ Wt, u16* __restrict__ Pb)
{
  __shared__ u16 sT[64 * 68];
  const int bid = blockIdx.x, t = threadIdx.x;
  if (bid < 4096) {
    const size_t base = (size_t)bid * 1024 + t * 4;
    const float4 v = *(const float4*)(x + base);
    const u32 lo = (u32)f2b(v.x) | ((u32)f2b(v.y) << 16);
    const u32 hi = (u32)f2b(v.z) | ((u32)f2b(v.w) << 16);
    *(uint2*)(xb + base) = make_uint2(lo, hi);
  } else if (bid < 4224) {
    const size_t base = (size_t)(bid - 4096) * 1024 + t * 4;
    const float4 v = *(const float4*)(P + base);
    const u32 lo = (u32)f2b(v.x) | ((u32)f2b(v.y) << 16);
    const u32 hi = (u32)f2b(v.z) | ((u32)f2b(v.w) << 16);
    *(uint2*)(Pb + base) = make_uint2(lo, hi);
  } else if (bid < 4992) {
    const int tb = bid - 4224;
    const int tk = tb / 48, tn = tb % 48;
    const int k0 = tk * 64, n0 = tn * 64;
#pragma unroll
    for (int it = 0; it < 4; ++it) {
      const int c = it * 256 + t;
      const int r = c >> 4, c4 = (c & 15) << 2;
      const float4 v = *(const float4*)(W + (size_t)(k0 + r) * 3072 + n0 + c4);
      sT[(c4 + 0) * 68 + r] = f2b(v.x);
      sT[(c4 + 1) * 68 + r] = f2b(v.y);
      sT[(c4 + 2) * 68 + r] = f2b(v.z);
      sT[(c4 + 3) * 68 + r] = f2b(v.w);
    }
    __syncthreads();
#pragma unroll
    for (int it = 0; it < 4; ++it) {
      const int c = it * 256 + t;
      const int rr = c >> 4, k4 = (c & 15) << 2;
      const uint2 rv = *(const uint2*)(sT + rr * 68 + k4);
      *(uint2*)(Wt + (size_t)(n0 + rr) * 1024 + k0 + k4) = rv;
    }
  } else {
    if (t < 64) Pb[2048 * 64 + t] = f2b(P[2047 * 64 + t]);  // guard row
  }
}

// ---------------------------------------------------------------------------
// qkv_gemm (bf16 MFMA): C = xb(4096x1024) @ Wt^T(1024x3072) + bias.
// 128x128 tile, BK=64, XOR-swizzled LDS, global_load_lds 16B, XCD-aware grid.
// Epilogue: LDS repack -> coalesced stores; V goes TRANSPOSED to Vt.
// ---------------------------------------------------------------------------
__global__ __launch_bounds__(256, 3) void qkv_gemm(
    const u16* __restrict__ xb, const u16* __restrict__ Wt,
    const float* __restrict__ bq,
    u16* __restrict__ Qh, u16* __restrict__ Kh, u16* __restrict__ Vt)
{
  __shared__ u16 smem[16384];        // 32 KB: sA | sB, reused as repack tile
  u16* const sA = smem;
  u16* const sB = smem + 8192;
  u16* const T  = smem;              // epilogue tile [64][136]
  const int t = threadIdx.x;
  const int lane = t & 63, w = t >> 6;
  const int l = lane & 15, ql = lane >> 4;
  const int wm = w & 1, wn = w >> 1;
  const int vid = blockIdx.x;
  const int xcd = vid & 7, jj = vid >> 3;          // jj in [0,96)
  const int n0 = (xcd * 3 + (jj % 3)) * 128;
  const int m0 = (jj / 3) * 128;

  f32x4 acc[4][4];
#pragma unroll
  for (int i = 0; i < 4; ++i)
#pragma unroll
    for (int j = 0; j < 4; ++j) acc[i][j] = (f32x4){0.f, 0.f, 0.f, 0.f};

  for (int k0 = 0; k0 < 1024; k0 += 64) {
    __syncthreads();
#pragma unroll
    for (int j = 0; j < 4; ++j) {
      const int ii = w * 4 + j;
      const int m = ii * 8 + (lane >> 3);
      const int q8 = (lane & 7) ^ (m & 7);
      __builtin_amdgcn_global_load_lds(
          (const AS1 u32*)(xb + (size_t)(m0 + m) * 1024 + k0 + q8 * 8),
          (AS3 u32*)(sA + ii * 512), 16, 0, 0);
      __builtin_amdgcn_global_load_lds(
          (const AS1 u32*)(Wt + (size_t)(n0 + m) * 1024 + k0 + q8 * 8),
          (AS3 u32*)(sB + ii * 512), 16, 0, 0);
    }
    __syncthreads();
#pragma unroll
    for (int ks = 0; ks < 2; ++ks) {
      bf16x8 a[4], b[4];
#pragma unroll
      for (int mt = 0; mt < 4; ++mt) {
        const int m = wm * 64 + mt * 16 + l;
        a[mt] = *(const bf16x8*)(sA + m * 64 + (((ks * 4 + ql) ^ (m & 7)) * 8));
      }
#pragma unroll
      for (int nt = 0; nt < 4; ++nt) {
        const int nn = wn * 64 + nt * 16 + l;
        b[nt] = *(const bf16x8*)(sB + nn * 64 + (((ks * 4 + ql) ^ (nn & 7)) * 8));
      }
#pragma unroll
      for (int mt = 0; mt < 4; ++mt)
#pragma unroll
        for (int nt = 0; nt < 4; ++nt)
          acc[mt][nt] = __builtin_amdgcn_mfma_f32_16x16x32_bf16(
              a[mt], b[nt], acc[mt][nt], 0, 0, 0);
    }
  }

  const int which = n0 >> 10;                 // 0=Q 1=K 2=V (uniform per block)
  const int qbase = m0 & 1023;
  const int bb = m0 >> 10;
  const int h0 = (n0 & 1023) >> 6;
#pragma unroll
  for (int pass = 0; pass < 2; ++pass) {
    __syncthreads();
    if (wm == pass) {
#pragma unroll
      for (int nt = 0; nt < 4; ++nt) {
        const int col = wn * 64 + nt * 16 + l;
        const float bias = bq[n0 + col];
#pragma unroll
        for (int mt = 0; mt < 4; ++mt)
#pragma unroll
          for (int rg = 0; rg < 4; ++rg)
            T[(mt * 16 + ql * 4 + rg) * 136 + col] = f2b(acc[mt][nt][rg] + bias);
      }
    }
    __syncthreads();
    if (which < 2) {
      u16* const dst = which ? Kh : Qh;
#pragma unroll
      for (int h = 0; h < 2; ++h) {
        const size_t bnoff = ((size_t)(bb * 16 + h0 + h)) << 16;
#pragma unroll
        for (int it = 0; it < 2; ++it) {
          const int c = it * 256 + t;
          const int r = c >> 3, d8 = (c & 7) * 8;
          const uint4 v = *(const uint4*)(T + r * 136 + h * 64 + d8);
          *(uint4*)(dst + bnoff + ((size_t)(qbase + pass * 64 + r) << 6) + d8) = v;
        }
      }
    } else {
#pragma unroll
      for (int h = 0; h < 2; ++h) {
        const size_t bnoff = ((size_t)(bb * 16 + h0 + h)) << 16;
#pragma unroll
        for (int it = 0; it < 2; ++it) {
          const int c = it * 256 + t;
          const int dr = c >> 3, q8 = (c & 7) * 8;
          u32 pk[4];
#pragma unroll
          for (int e = 0; e < 4; ++e) {
            const u16 lo = T[(q8 + 2 * e + 0) * 136 + h * 64 + dr];
            const u16 hi = T[(q8 + 2 * e + 1) * 136 + h * 64 + dr];
            pk[e] = (u32)lo | ((u32)hi << 16);
          }
          *(uint4*)(Vt + bnoff + ((size_t)dr << 10) + qbase + pass * 64 + q8) =
              make_uint4(pk[0], pk[1], pk[2], pk[3]);
        }
      }
    }
  }
}

// ---------------------------------------------------------------------------
// rel_attn (bf16 MFMA flash, no-max softmax): 128-row q-tile per block,
// 32 rows per wave (2 MFMA row-tiles). Grid 512 = 8 q-tiles x 64 heads;
// vid&7 == bn&7 keeps each head's q-tiles on one XCD.
// Per wave-iter: z1 = U.K^T (2mt x 4nt, shared bk), z2 = W.Pband^T
// (6 shared B-tiles, 5 MFMAs per mt), diagonal gather (shift c'=127-i:
// c'&15 uniform per (ql,reg), tile base 7-(2w+mt) uniform per (wave,mt)),
// exp2 probs (no max - scores bounded), PV vs shared V^T tile.
// DS b128 reads/unit: 16 vs 28 in the 64-row version. LDS 48 KB.
// ---------------------------------------------------------------------------
__global__ __launch_bounds__(256, 2) void rel_attn(
    const u16* __restrict__ Qh, const u16* __restrict__ Kh,
    const u16* __restrict__ Vt, const u16* __restrict__ Pb,
    const float* __restrict__ rrb, const float* __restrict__ rwb,
    float* __restrict__ out)
{
  __shared__ u16 smem[24576];        // 49152 B
  u16* const sK    = smem;           // [64][64]  swizzled
  u16* const sVT   = smem + 4096;    // [64][64]  swizzled (rows=d, cols=j)
  u16* const sProb = smem + 8192;    // [128][32] swizzled half-tile
  u16* const sP    = smem + 12288;   // [192][64] swizzled
  u16* const sU    = smem;           // transient alias [128][64]
  u16* const sW    = smem + 8192;    // transient alias [128][64]

  const int t = threadIdx.x;
  const int lane = t & 63, w = t >> 6;
  const int l = lane & 15, ql = lane >> 4;
  const int vid = blockIdx.x;
  const int qt = vid >> 6, bn = vid & 63;          // vid&7 == bn&7 (XCD)
  const int n = bn & 15, bb = bn >> 4;
  const size_t hoff = (size_t)bn << 16;
  const int q0 = qt << 7;
  const int bz = 6 - 2 * w;                        // z2 rel-tile base

  // stage U = Q+rr, W = Q+rw+K (128 query rows), swizzled pitch-64
#pragma unroll
  for (int it = 0; it < 4; ++it) {
    const int c = it * 256 + t;
    const int i = c >> 3, ch = c & 7;
    const int d8 = ch * 8;
    const uint4 qv = *(const uint4*)(Qh + hoff + ((size_t)(q0 + i) << 6) + d8);
    const uint4 kv = *(const uint4*)(Kh + hoff + ((size_t)(q0 + i) << 6) + d8);
    const u16* qp = (const u16*)&qv;
    const u16* kp = (const u16*)&kv;
    u16 uo[8], wo[8];
#pragma unroll
    for (int e = 0; e < 8; ++e) {
      const float rv = rrb[n * 64 + d8 + e];
      const float wv = rwb[n * 64 + d8 + e];
      const float qf = b2f(qp[e]), kf = b2f(kp[e]);
      uo[e] = f2b(qf + rv);
      wo[e] = f2b(qf + wv + kf);
    }
    const int pos = i * 64 + ((ch ^ (i & 7)) * 8);
    *(uint4*)(sU + pos) = *(const uint4*)uo;
    *(uint4*)(sW + pos) = *(const uint4*)wo;
  }
  __syncthreads();

  bf16x8 au[2][2], aw[2][2];         // [mt][ks], loop-invariant A-frags
#pragma unroll
  for (int mt = 0; mt < 2; ++mt)
#pragma unroll
    for (int ks = 0; ks < 2; ++ks) {
      const int row = w * 32 + mt * 16 + l;
      const int off = row * 64 + (((ks * 4 + ql) ^ (row & 7)) * 8);
      au[mt][ks] = *(const bf16x8*)(sU + off);
      aw[mt][ks] = *(const bf16x8*)(sW + off);
    }

  f32x4 o[2][4];
  float lrun[2][4];
#pragma unroll
  for (int mt = 0; mt < 2; ++mt)
#pragma unroll
    for (int ii = 0; ii < 4; ++ii) {
      o[mt][ii] = (f32x4){0.f, 0.f, 0.f, 0.f};
      lrun[mt][ii] = 0.f;
    }

  for (int k0 = 0; k0 < 1024; k0 += 64) {
    const int lbase = 897 + k0 - q0;   // 1024+k0-q0-127, in [1,1857]
    __syncthreads();
    // async staging: sK (2 calls/wave), sVT (2), sP (6: 192 rows)
#pragma unroll
    for (int j = 0; j < 2; ++j) {
      const int ii = w * 2 + j;
      const int m = ii * 8 + (lane >> 3);
      const int q8 = (lane & 7) ^ (m & 7);
      __builtin_amdgcn_global_load_lds(
          (const AS1 u32*)(Kh + hoff + ((size_t)(k0 + m) << 6) + q8 * 8),
          (AS3 u32*)(sK + ii * 512), 16, 0, 0);
      __builtin_amdgcn_global_load_lds(
          (const AS1 u32*)(Vt + hoff + ((size_t)m << 10) + k0 + q8 * 8),
          (AS3 u32*)(sVT + ii * 512), 16, 0, 0);
    }
#pragma unroll
    for (int j = 0; j < 6; ++j) {
      const int ii = w * 6 + j;
      const int m = ii * 8 + (lane >> 3);
      const int q8 = (lane & 7) ^ (m & 7);
      __builtin_amdgcn_global_load_lds(
          (const AS1 u32*)(Pb + ((size_t)(lbase + m) << 6) + q8 * 8),
          (AS3 u32*)(sP + ii * 512), 16, 0, 0);
    }
    __syncthreads();

    f32x4 z1[2][4], z2[2][5];
#pragma unroll
    for (int mt = 0; mt < 2; ++mt) {
#pragma unroll
      for (int i = 0; i < 4; ++i) z1[mt][i] = (f32x4){0.f, 0.f, 0.f, 0.f};
#pragma unroll
      for (int i = 0; i < 5; ++i) z2[mt][i] = (f32x4){0.f, 0.f, 0.f, 0.f};
    }
#pragma unroll
    for (int ks = 0; ks < 2; ++ks) {
#pragma unroll
      for (int nt = 0; nt < 4; ++nt) {
        const int row = nt * 16 + l;
        const bf16x8 bk =
            *(const bf16x8*)(sK + row * 64 + (((ks * 4 + ql) ^ (row & 7)) * 8));
#pragma unroll
        for (int mt = 0; mt < 2; ++mt)
          z1[mt][nt] = __builtin_amdgcn_mfma_f32_16x16x32_bf16(
              au[mt][ks], bk, z1[mt][nt], 0, 0, 0);
      }
      // 6 shared P B-tiles; mt=0 uses rel tiles 1..5, mt=1 uses 0..4
#pragma unroll
      for (int rt = 0; rt < 6; ++rt) {
        const int row = (bz + rt) * 16 + l;
        const bf16x8 bp =
            *(const bf16x8*)(sP + row * 64 + (((ks * 4 + ql) ^ (row & 7)) * 8));
        if (rt >= 1)
          z2[0][rt - 1] = __builtin_amdgcn_mfma_f32_16x16x32_bf16(
              aw[0][ks], bp, z2[0][rt - 1], 0, 0, 0);
        if (rt <= 4)
          z2[1][rt] = __builtin_amdgcn_mfma_f32_16x16x32_bf16(
              aw[1][ks], bp, z2[1][rt], 0, 0, 0);
      }
    }

    // diagonal gather + exp2 (rows i = 32w + 16mt + 4ql + ii)
    float p[2][4][4];
#pragma unroll
    for (int mt = 0; mt < 2; ++mt)
#pragma unroll
      for (int ii = 0; ii < 4; ++ii) {
        const int ci = 15 - ql * 4 - ii;               // c' & 15
        const int src = (lane & 48) | ((l + ci) & 15);
        const bool wrap = l < ci;
#pragma unroll
        for (int jt = 0; jt < 4; ++jt) {
          const float val = wrap ? z2[mt][jt + 1][ii] : z2[mt][jt][ii];
          const float g = __shfl(val, src, 64);
          const float pv = exp2f((z1[mt][jt][ii] + g) * 0.18033688011112042f);
          p[mt][ii][jt] = pv;
          lrun[mt][ii] += pv;
        }
      }

    // PV in two K=32 steps through the half-tile wave-private prob buffer
#pragma unroll
    for (int ks = 0; ks < 2; ++ks) {
#pragma unroll
      for (int mt = 0; mt < 2; ++mt)
#pragma unroll
        for (int ii = 0; ii < 4; ++ii) {
          const int r = w * 32 + mt * 16 + ql * 4 + ii;
          const int sw2 = (r & 3) ^ ((r >> 2) & 3);
#pragma unroll
          for (int jh = 0; jh < 2; ++jh) {
            const int ch = jh * 2 + (l >> 3);
            sProb[r * 32 + ((ch ^ sw2) * 8) + (l & 7)] =
                f2b_fast(p[mt][ii][ks * 2 + jh]);
          }
        }
      bf16x8 bv[4];
#pragma unroll
      for (int dt = 0; dt < 4; ++dt) {
        const int row = dt * 16 + l;
        bv[dt] =
            *(const bf16x8*)(sVT + row * 64 + (((ks * 4 + ql) ^ (row & 7)) * 8));
      }
#pragma unroll
      for (int mt = 0; mt < 2; ++mt) {
        const int ar = w * 32 + mt * 16 + l;
        const bf16x8 ap = *(const bf16x8*)(
            sProb + ar * 32 + ((ql ^ ((ar & 3) ^ ((ar >> 2) & 3))) * 8));
#pragma unroll
        for (int dt = 0; dt < 4; ++dt)
          o[mt][dt] = __builtin_amdgcn_mfma_f32_16x16x32_bf16(
              ap, bv[dt], o[mt][dt], 0, 0, 0);
      }
    }
  }

  // epilogue: row-sum reduce, normalize, store fp32 (B, L, D)
#pragma unroll
  for (int mt = 0; mt < 2; ++mt)
#pragma unroll
    for (int ii = 0; ii < 4; ++ii) {
      float ls = lrun[mt][ii];
      ls += __shfl_xor(ls, 1);
      ls += __shfl_xor(ls, 2);
      ls += __shfl_xor(ls, 4);
      ls += __shfl_xor(ls, 8);
      const float inv = 1.f / ls;
      const int q = q0 + w * 32 + mt * 16 + ql * 4 + ii;
#pragma unroll
      for (int dt = 0; dt < 4; ++dt)
        out[((size_t)(bb * 1024 + q) << 10) + (n << 6) + dt * 16 + l] =
            o[mt][dt][ii] * inv;
    }
}

// ---------------------------------------------------------------------------
extern "C" void kernel_launch(void* const* d_in, const int* in_sizes, int n_in,
                              void* d_out, int out_size, void* d_ws, size_t ws_size,
                              hipStream_t stream) {
  const float* x  = (const float*)d_in[0];  // (4,1024,1024)
  const float* P  = (const float*)d_in[1];  // (2048,64)
  const float* Wq = (const float*)d_in[2];  // (1024,3072)
  const float* bq = (const float*)d_in[3];  // (3072,)
  const float* rr = (const float*)d_in[4];  // (16,64)
  const float* rw = (const float*)d_in[5];  // (16,64)
  float* out = (float*)d_out;

  char* ws = (char*)d_ws;
  u16* xb = (u16*)(ws);                      // 8 MB
  u16* Wt = (u16*)(ws + 8388608);            // 6 MB  [3072][1024]
  u16* Pb = (u16*)(ws + 14680064);           // 2049 rows x 64 (+guard)
  u16* Qh = (u16*)(ws + 14946304);           // 8 MB  [bn][q][d]
  u16* Kh = (u16*)(ws + 23334912);           // 8 MB
  u16* Vt = (u16*)(ws + 31723520);           // 8 MB  [bn][d][q]

  prep<<<4993, 256, 0, stream>>>(x, Wq, P, xb, Wt, Pb);
  qkv_gemm<<<768, 256, 0, stream>>>(xb, Wt, bq, Qh, Kh, Vt);
  rel_attn<<<512, 256, 0, stream>>>(Qh, Kh, Vt, Pb, rr, rw, out);
}